// Round 5
// baseline (221.202 us; speedup 1.0000x reference)
//
#include <hip/hip_runtime.h>
#include <hip/hip_fp16.h>
#include <math.h>

#define NSLOTS 4096
#define DIM    128
#define HDIM   1024
#define NTOK   16384   // 4 * 4096
#define SCALE  0.08838834764831845f  // 1/sqrt(128)
#define REPS   1e-10f

typedef __attribute__((ext_vector_type(8))) short bf16x8;
typedef __attribute__((ext_vector_type(4))) float f32x4;

typedef __attribute__((address_space(1))) const void* as1cv;
typedef __attribute__((address_space(3))) void* as3v;

// ---- packed (score | 4095-slot) helpers -----------------------------------
// Low 12 mantissa bits replaced by (4095-slot): float compare = score desc,
// then slot asc. fp32 rescue re-ranks the 16-candidate pool exactly, so only
// pool membership at the noise margin matters. Top-8-per-lane guarantees the
// true bf16-top-8 is always in the pool (≤7 elements outrank it anywhere).
__device__ __forceinline__ float pack_score(float biased, unsigned inv_idx) {
    return __uint_as_float((__float_as_uint(biased) & 0xFFFFF000u) | inv_idx);
}
#define PACK_NEG_INF __uint_as_float(0xFF7FF000u)   // ~ -FLT_MAX, valid finite

// Branchless insert into ascending sorted r[0..7] (r[7]=max), drop min.
__device__ __forceinline__ void ins_packed(float (&r)[8], float x) {
    #pragma unroll
    for (int i = 0; i < 7; ++i) r[i] = __builtin_amdgcn_fmed3f(r[i], x, r[i + 1]);
    r[7] = fmaxf(r[7], x);
}

// Pop-merge 4 kseg-lanes' sorted top-8 (32 values) -> sorted top-16 (desc,
// packed) into LDS. Group = lanes {l, l^16, l^32, l^48}.
__device__ __forceinline__ void merge_out16(float (&r)[8], int kseg, float* outS) {
    float hv = r[7];
    #pragma unroll
    for (int rnd = 0; rnd < 16; ++rnd) {
        float bv = hv;
        bv = fmaxf(bv, __shfl_xor(bv, 16, 64));
        bv = fmaxf(bv, __shfl_xor(bv, 32, 64));
        if ((rnd >> 2) == kseg) outS[rnd] = bv;   // each kseg-lane writes 4
        if (hv == bv) {   // my head won (packed values distinct in group): pop
            #pragma unroll
            for (int m2 = 7; m2 > 0; --m2) r[m2] = r[m2 - 1];
            r[0] = PACK_NEG_INF;
            hv = r[7];
        }
    }
}

// ---------------- kernel 0: prep (bf16 q/k + fp16 V + log-rel) --------------
__device__ __forceinline__ ushort f2bf(float f) {   // RNE
    unsigned u = __float_as_uint(f);
    return (ushort)((u + 0x7fffu + ((u >> 16) & 1u)) >> 16);
}
// kbp chunk C (16 B = 8 bf16): C = t16*256 + kc*64 + l
//   t16 = 16-slot tile (0..255), kc = K-chunk (0..3), l = lane
//   source = keys[slot = t16*16 + (l&15)][kc*32 + (l>>4)*8 .. +8)
#define QB_N  524288   // q bf16 convert, float4 granules
#define KBP_N 65536    // k permuted bf16 chunks
#define LR_N  4096     // log-reliability
#define VH_N  524288   // V fp16 convert, 8 floats per thread
__global__ void prep_kernel(const float* __restrict__ q, const float* __restrict__ k,
                            const float* __restrict__ rel, const float* __restrict__ v,
                            ushort* __restrict__ qb, ushort* __restrict__ kbp,
                            float* __restrict__ lr, ushort* __restrict__ vh) {
    int gid = blockIdx.x * 256 + threadIdx.x;
    if (gid < QB_N) {                         // qb row-major: 2,097,152 floats / 4
        float4 vv = ((const float4*)q)[gid];
        ushort4 o; o.x = f2bf(vv.x); o.y = f2bf(vv.y); o.z = f2bf(vv.z); o.w = f2bf(vv.w);
        ((ushort4*)qb)[gid] = o;
    } else if (gid < QB_N + KBP_N) {          // kbp fragment-permuted chunks
        int C = gid - QB_N;
        int l = C & 63, kc = (C >> 6) & 3, t16 = C >> 8;
        int slot = t16 * 16 + (l & 15);
        int doff = kc * 32 + (l >> 4) * 8;
        const float4* src = (const float4*)(k + (size_t)slot * DIM + doff);
        float4 v0 = src[0], v1 = src[1];
        union { ushort u[8]; uint4 v; } o;
        o.u[0] = f2bf(v0.x); o.u[1] = f2bf(v0.y); o.u[2] = f2bf(v0.z); o.u[3] = f2bf(v0.w);
        o.u[4] = f2bf(v1.x); o.u[5] = f2bf(v1.y); o.u[6] = f2bf(v1.z); o.u[7] = f2bf(v1.w);
        ((uint4*)kbp)[C] = o.v;
    } else if (gid < QB_N + KBP_N + LR_N) {
        int g = gid - QB_N - KBP_N;
        lr[g] = logf(rel[g] + REPS);
    } else if (gid < QB_N + KBP_N + LR_N + VH_N) {   // V fp32 -> fp16 (RNE)
        int g = gid - QB_N - KBP_N - LR_N;
        const float4* src = (const float4*)v + (size_t)g * 2;
        float4 a = src[0], b = src[1];
        union { _Float16 h[8]; uint4 u; } o;
        o.h[0] = (_Float16)a.x; o.h[1] = (_Float16)a.y;
        o.h[2] = (_Float16)a.z; o.h[3] = (_Float16)a.w;
        o.h[4] = (_Float16)b.x; o.h[5] = (_Float16)b.y;
        o.h[6] = (_Float16)b.z; o.h[7] = (_Float16)b.w;
        ((uint4*)vh)[g] = o.u;
    }
}

// ---------------- kernel 1: MFMA router + packed top-8 ----------------------
// Grid 512 x 256 thr (4 waves). Block = 32 tokens, all 4096 slots; wave w =
// slot quarter (1024 slots = 64 tiles of 16). K tiles staged to PER-WAVE LDS
// double-buffers via global_load_lds (no VGPR cost, no spills) with counted
// s_waitcnt vmcnt(4) — NO barriers in the loop (each wave owns its buffers).
// vmcnt audit: queue at iter t's wait = [tile_t x4, tile_{t+1} x4, lrv_{t-1}];
// wait-to-4 retires tile_t (+ at most 1 prefetch load). asm "memory" clobbers
// pin all VMEM ops inside their iteration, so the count cannot drift.
// Each tile feeds TWO 16-token MFMA column blocks -> kbp L2 traffic 512 MB.
// LDS = 4x2x4KB kbuf + 8KB qS = 40 KB exactly -> 4 blocks/CU = 16 waves/CU.
// Per-lane top-8 over its 256-slot partition; 4-lane merge -> quarter top-16;
// 4-way merge -> approx top-16 pool (contains exact bf16 top-8) -> cand.
__launch_bounds__(256, 4)
__global__ void route_kernel(const ushort* __restrict__ qb,
                             const ushort* __restrict__ kbp,
                             const float*  __restrict__ lr,
                             int* __restrict__ cand) {
    __shared__ ushort ktile[4][2][4 * 512];   // [wave][buf][4KB tile] = 32 KB
    __shared__ float  qS[32][4][16];          // [token][quarter][16] = 8 KB
    const int tid  = threadIdx.x;
    const int lane = tid & 63;
    const int w    = tid >> 6;     // wave = slot quarter 0..3
    const int m    = lane & 15;    // token col
    const int kseg = lane >> 4;
    const int tokbase = blockIdx.x * 32;

    // stationary B-frags (queries) for both 16-token halves
    bf16x8 bF0[4], bF1[4];
    const ushort* q0 = qb + (size_t)(tokbase + m) * DIM + kseg * 8;
    const ushort* q1 = qb + (size_t)(tokbase + 16 + m) * DIM + kseg * 8;
    #pragma unroll
    for (int kc = 0; kc < 4; ++kc) {
        bF0[kc] = *(const bf16x8*)(q0 + kc * 32);
        bF1[kc] = *(const bf16x8*)(q1 + kc * 32);
    }

    float R0[8], R1[8];
    #pragma unroll
    for (int i = 0; i < 8; ++i) { R0[i] = PACK_NEG_INF; R1[i] = PACK_NEG_INF; }

    // DMA one 16-slot tile (4 KB = 4 chunks x 64 lanes x 16 B) into wave buf
    auto issue = [&](int t, int buf) {
        const ushort* gt = kbp + ((size_t)((w * 64 + t) * 256 + lane)) * 8;
        ushort* lb = &ktile[w][buf][0];
        #pragma unroll
        for (int i = 0; i < 4; ++i) {
            __builtin_amdgcn_global_load_lds((as1cv)(gt + i * 512),
                                             (as3v)(lb + i * 512 + lane * 8), 16, 0, 0);
        }
    };

    issue(0, 0);
    issue(1, 1);

    for (int t = 0; t < 64; ++t) {
        const int cur = t & 1;
        if (t < 63) {
            asm volatile("s_waitcnt vmcnt(4)" ::: "memory");
        } else {
            asm volatile("s_waitcnt vmcnt(0)" ::: "memory");
        }
        const ushort* kt = &ktile[w][cur][0];
        bf16x8 aF[4];
        #pragma unroll
        for (int kc = 0; kc < 4; ++kc)
            aF[kc] = *(const bf16x8*)(kt + kc * 512 + lane * 8);
        // ds_reads drained, then refill the buffer we just consumed
        asm volatile("s_waitcnt lgkmcnt(0)" ::: "memory");
        if (t < 62) issue(t + 2, cur);

        f32x4 acc0 = {0.f, 0.f, 0.f, 0.f};
        f32x4 acc1 = {0.f, 0.f, 0.f, 0.f};
        #pragma unroll
        for (int kc = 0; kc < 4; ++kc) {
            acc0 = __builtin_amdgcn_mfma_f32_16x16x32_bf16(aF[kc], bF0[kc], acc0, 0, 0, 0);
            acc1 = __builtin_amdgcn_mfma_f32_16x16x32_bf16(aF[kc], bF1[kc], acc1, 0, 0, 0);
        }
        const int base = w * 1024 + t * 16;
        float4 lrv = ((const float4*)lr)[(base >> 2) + kseg];
        unsigned invb = 4095u - (unsigned)(base + kseg * 4);
        ins_packed(R0, pack_score(acc0[0] + lrv.x, invb));
        ins_packed(R0, pack_score(acc0[1] + lrv.y, invb - 1));
        ins_packed(R0, pack_score(acc0[2] + lrv.z, invb - 2));
        ins_packed(R0, pack_score(acc0[3] + lrv.w, invb - 3));
        ins_packed(R1, pack_score(acc1[0] + lrv.x, invb));
        ins_packed(R1, pack_score(acc1[1] + lrv.y, invb - 1));
        ins_packed(R1, pack_score(acc1[2] + lrv.z, invb - 2));
        ins_packed(R1, pack_score(acc1[3] + lrv.w, invb - 3));
    }

    merge_out16(R0, kseg, &qS[m][w][0]);
    merge_out16(R1, kseg, &qS[m + 16][w][0]);
    __syncthreads();

    // 4-way merge of the quarters' sorted-desc lists -> global approx top-16
    if (tid < 32) {
        const int token = tokbase + tid;
        int p[4] = {0, 0, 0, 0};
        #pragma unroll
        for (int c = 0; c < 16; ++c) {
            float bv = -INFINITY; int bq = 0;
            #pragma unroll
            for (int j = 0; j < 4; ++j) {
                float v = (p[j] < 16) ? qS[tid][j][p[j]] : -INFINITY;
                if (v > bv) { bv = v; bq = j; }
            }
            cand[(size_t)token * 16 + c] = 4095 - (int)(__float_as_uint(bv) & 0xFFFu);
            ++p[bq];
        }
    }
}

// ---------------- kernel 2: fused fp32 rescue + softmax + V gather ----------
// 512 thr = 8 waves = 4 tokens x 2 gather-waves. Both waves of a token run
// the identical in-register score/sort/softmax (deterministic), then each
// gathers 4 of the 8 weighted fp16 V rows; partials combine through LDS.
// Doubles waves and outstanding gather loads per SIMD -> attacks the
// latency-bound TCC-miss path (2 TB/s observed). launch_bounds(512,4):
// VGPR cap 128 (no spill risk); actual ~56 VGPR still gives 8 waves/SIMD.
__device__ __forceinline__ float2 h2f2(unsigned u) {
    return __half22float2(*reinterpret_cast<const __half2*>(&u));
}
__launch_bounds__(512, 4)
__global__ void rescue_gather_kernel(const float* __restrict__ query,
                                     const float* __restrict__ keys,
                                     const float* __restrict__ lr,
                                     const int*   __restrict__ cand,
                                     const ushort* __restrict__ vh,
                                     float* __restrict__ out,
                                     float* __restrict__ wout) {
    __shared__ float4 pbuf[4][4][64];   // parity-1 partials, 16 KB
    const int tid  = threadIdx.x;
    const int wv   = tid >> 6;
    const int tw   = wv >> 1;    // token-in-block 0..3
    const int par  = wv & 1;     // candidate half
    const int lane = tid & 63;
    const int token = blockIdx.x * 4 + tw;
    const int c  = lane >> 2;    // candidate 0..15
    const int qp = lane & 3;     // dim quarter (32 floats)

    int ci = cand[(size_t)token * 16 + c];
    const float4* q4 = (const float4*)(query + (size_t)token * DIM) + qp * 8;
    const float4* k4 = (const float4*)(keys  + (size_t)ci    * DIM) + qp * 8;
    float sum = 0.f;
    #pragma unroll
    for (int i = 0; i < 8; ++i) {
        float4 a = q4[i], b = k4[i];
        sum = fmaf(a.x, b.x, sum); sum = fmaf(a.y, b.y, sum);
        sum = fmaf(a.z, b.z, sum); sum = fmaf(a.w, b.w, sum);
    }
    sum += __shfl_xor(sum, 1, 4);
    sum += __shfl_xor(sum, 2, 4);    // all 4 twins hold the full dot
    float raw = sum;
    float s   = sum + lr[ci];        // biased, exact fp32

    // bitonic sort of 16 candidates across lanes (twins mirror; partner lane
    // = lane ^ (j*4)). "mineFirst" = ranks before = (s desc, idx asc).
    #pragma unroll
    for (int k = 2; k <= 16; k <<= 1) {
        #pragma unroll
        for (int j = k >> 1; j >= 1; j >>= 1) {
            int off = j << 2;
            float s2 = __shfl_xor(s,   off, 64);
            float r2 = __shfl_xor(raw, off, 64);
            int   i2 = __shfl_xor(ci,  off, 64);
            bool mineFirst = (s > s2) || (s == s2 && ci < i2);
            bool lower = (c & j) == 0;
            bool asc   = (c & k) == 0;
            bool keep  = (lower == asc) ? mineFirst : !mineFirst;
            if (!keep) { s = s2; raw = r2; ci = i2; }
        }
    }
    // position c now holds rank c; broadcast top-8 (raw, idx) to all lanes
    float rsel[8]; int isel[8];
    #pragma unroll
    for (int r = 0; r < 8; ++r) {
        rsel[r] = __shfl(raw, r * 4, 64);
        isel[r] = __shfl(ci,  r * 4, 64);
    }

    // softmax on raw*SCALE — redundantly in every lane of both waves
    float mx = -INFINITY;
    #pragma unroll
    for (int k = 0; k < 8; ++k) { rsel[k] *= SCALE; mx = fmaxf(mx, rsel[k]); }
    float e[8]; float ssum = 0.f;
    #pragma unroll
    for (int k = 0; k < 8; ++k) { e[k] = expf(rsel[k] - mx); ssum += e[k]; }
    float inv = 1.0f / ssum;
    float wk[8];
    #pragma unroll
    for (int k = 0; k < 8; ++k) wk[k] = e[k] * inv;

    if (par == 0 && lane == 0) {
        #pragma unroll
        for (int k = 0; k < 8; ++k) wout[(size_t)token * 8 + k] = wk[k];
    }

    // gather this wave's 4 candidates: fp16 rows, lane owns dims
    // [lane*8, lane*8+8) and [512+lane*8, 512+lane*8+8)
    float oA[8], oB[8];
    #pragma unroll
    for (int i = 0; i < 8; ++i) { oA[i] = 0.f; oB[i] = 0.f; }
    #pragma unroll
    for (int kk = 0; kk < 4; ++kk) {
        const int k = par * 4 + kk;
        const uint4* vr = (const uint4*)vh + (size_t)isel[k] * 128;
        float wkk = wk[k];
        uint4 va = vr[lane];
        uint4 vb = vr[lane + 64];
        float2 f;
        f = h2f2(va.x); oA[0] = fmaf(wkk, f.x, oA[0]); oA[1] = fmaf(wkk, f.y, oA[1]);
        f = h2f2(va.y); oA[2] = fmaf(wkk, f.x, oA[2]); oA[3] = fmaf(wkk, f.y, oA[3]);
        f = h2f2(va.z); oA[4] = fmaf(wkk, f.x, oA[4]); oA[5] = fmaf(wkk, f.y, oA[5]);
        f = h2f2(va.w); oA[6] = fmaf(wkk, f.x, oA[6]); oA[7] = fmaf(wkk, f.y, oA[7]);
        f = h2f2(vb.x); oB[0] = fmaf(wkk, f.x, oB[0]); oB[1] = fmaf(wkk, f.y, oB[1]);
        f = h2f2(vb.y); oB[2] = fmaf(wkk, f.x, oB[2]); oB[3] = fmaf(wkk, f.y, oB[3]);
        f = h2f2(vb.z); oB[4] = fmaf(wkk, f.x, oB[4]); oB[5] = fmaf(wkk, f.y, oB[5]);
        f = h2f2(vb.w); oB[6] = fmaf(wkk, f.x, oB[6]); oB[7] = fmaf(wkk, f.y, oB[7]);
    }

    if (par) {
        pbuf[tw][0][lane] = make_float4(oA[0], oA[1], oA[2], oA[3]);
        pbuf[tw][1][lane] = make_float4(oA[4], oA[5], oA[6], oA[7]);
        pbuf[tw][2][lane] = make_float4(oB[0], oB[1], oB[2], oB[3]);
        pbuf[tw][3][lane] = make_float4(oB[4], oB[5], oB[6], oB[7]);
    }
    __syncthreads();
    if (!par) {
        float4 pA0 = pbuf[tw][0][lane], pA1 = pbuf[tw][1][lane];
        float4 pB0 = pbuf[tw][2][lane], pB1 = pbuf[tw][3][lane];
        float4* orow = (float4*)(out + (size_t)token * HDIM);
        orow[lane * 2]           = make_float4(oA[0] + pA0.x, oA[1] + pA0.y,
                                               oA[2] + pA0.z, oA[3] + pA0.w);
        orow[lane * 2 + 1]       = make_float4(oA[4] + pA1.x, oA[5] + pA1.y,
                                               oA[6] + pA1.z, oA[7] + pA1.w);
        orow[128 + lane * 2]     = make_float4(oB[0] + pB0.x, oB[1] + pB0.y,
                                               oB[2] + pB0.z, oB[3] + pB0.w);
        orow[128 + lane * 2 + 1] = make_float4(oB[4] + pB1.x, oB[5] + pB1.y,
                                               oB[6] + pB1.z, oB[7] + pB1.w);
    }
}

// ---------------- launch ----------------
extern "C" void kernel_launch(void* const* d_in, const int* in_sizes, int n_in,
                              void* d_out, int out_size, void* d_ws, size_t ws_size,
                              hipStream_t stream) {
    const float* query  = (const float*)d_in[0];
    const float* keys   = (const float*)d_in[1];
    const float* values = (const float*)d_in[2];
    const float* rel    = (const float*)d_in[3];

    float* out  = (float*)d_out;                 // [16384, 1024]
    float* wout = out + (size_t)NTOK * HDIM;     // [16384, 8]

    char* ws = (char*)d_ws;
    float*  lr   = (float*)ws;   ws += 4096 * 4;                    // 16 KB
    ushort* qb   = (ushort*)ws;  ws += (size_t)NTOK * DIM * 2;      // 4 MB
    ushort* kbp  = (ushort*)ws;  ws += (size_t)NSLOTS * DIM * 2;    // 1 MB
    int*    cand = (int*)ws;     ws += (size_t)NTOK * 16 * 4;       // 1 MB
    ushort* vh   = (ushort*)ws;                                     // 8 MB fp16 V

    int prep_grid = (QB_N + KBP_N + LR_N + VH_N) / 256;   // = 4368
    hipLaunchKernelGGL(prep_kernel, dim3(prep_grid), dim3(256), 0, stream,
                       query, keys, rel, values, qb, kbp, lr, vh);
    hipLaunchKernelGGL(route_kernel, dim3(NTOK / 32), dim3(256), 0, stream,
                       qb, kbp, lr, cand);
    hipLaunchKernelGGL(rescue_gather_kernel, dim3(NTOK / 4), dim3(512), 0, stream,
                       query, keys, lr, cand, vh, out, wout);
}